// Round 9
// baseline (34.890 us; speedup 1.0000x reference)
//
#include <hip/hip_runtime.h>

#define NF 17
#define NN 23
#define ED 16
#define BLK 1024
#define RPP 256      // rows per pass = BLK/4
#define RPB 512      // rows per block (2 passes); grid*RPB == nrows exactly
#define SROWS 862    // packed rows of the 14 small-vocab fields
#define SSTR 18      // floats per LDS table row (72 B): 16 even start-banks

typedef int   int4u   __attribute__((ext_vector_type(4), aligned(4)));
typedef float float4u __attribute__((ext_vector_type(4), aligned(4)));
typedef float float2u __attribute__((ext_vector_type(2), aligned(4)));

__device__ __forceinline__ void acc4(const float4 v, float& s0, float& s1,
                                     float& s2, float& s3, float& sq) {
    s0 += v.x; s1 += v.y; s2 += v.z; s3 += v.w;
    sq += v.x * v.x + v.y * v.y + v.z * v.z + v.w * v.w;
}

__global__ __launch_bounds__(BLK, 8) void ffm_fwd_kernel(
    const int* __restrict__ x_cat,
    const float* __restrict__ x_num,
    const float* __restrict__ table,
    const float* __restrict__ W_num,
    const float* __restrict__ bias,
    float* __restrict__ out,
    int nrows)
{
    __shared__ float    tab[SROWS * SSTR];   // 62,064 B
    __shared__ unsigned prl[2 * RPP * 7];    // 14,336 B: u16 pairs of pre-scaled pr*18
    __shared__ float    wsum[24];            // padded; wsum[23] = 0

    const int tid = threadIdx.x;
    const int rl  = tid >> 2;   // local row within pass
    const int g   = tid & 3;    // dim-group: dims [4g, 4g+4)
    const int wb  = 6 * g;

    const int row0 = blockIdx.x * RPB + rl;    // grid*RPB == nrows, no guards
    const int row1 = row0 + RPP;

    // ================= PROLOGUE: issue ALL high-latency loads =================
    const int* xc0p = x_cat + (size_t)row0 * NF;
    const int4u a0 = *(const int4u*)(xc0p);
    const int4u a1 = *(const int4u*)(xc0p + 4);
    const int4u a2 = *(const int4u*)(xc0p + 8);
    const int4u a3 = *(const int4u*)(xc0p + 12);
    const int  a16 = xc0p[16];
    const int* xc1p = x_cat + (size_t)row1 * NF;
    const int4u c0 = *(const int4u*)(xc1p);
    const int4u c1 = *(const int4u*)(xc1p + 4);
    const int4u c2 = *(const int4u*)(xc1p + 8);
    const int4u c3 = *(const int4u*)(xc1p + 12);
    const int  c16 = xc1p[16];

    // 6 big-field gathers (f4, f10, f14 for both rows) — in flight across staging
    const float4 gv00 = *(const float4*)(table + (size_t)(a1.x +     653) * ED + g * 4);
    const float4 gv01 = *(const float4*)(table + (size_t)(a2.z + 1000787) * ED + g * 4);
    const float4 gv02 = *(const float4*)(table + (size_t)(a3.z + 1001846) * ED + g * 4);
    const float4 gv10 = *(const float4*)(table + (size_t)(c1.x +     653) * ED + g * 4);
    const float4 gv11 = *(const float4*)(table + (size_t)(c2.z + 1000787) * ED + g * 4);
    const float4 gv12 = *(const float4*)(table + (size_t)(c3.z + 1001846) * ED + g * 4);

    // pass-0 numeric slice
    const float* xp0 = x_num + (size_t)row0 * NN;
    const float4u xa0 = *(const float4u*)(xp0 + wb);
    float xb0_0, xb1_0;
    if (g < 3) { const float2u t = *(const float2u*)(xp0 + wb + 4); xb0_0 = t.x; xb1_0 = t.y; }
    else       { xb0_0 = xp0[22]; xb1_0 = 0.f; }

    // Park both passes' pre-scaled LDS row offsets (pr*18 <= 15498 fits u16);
    // frees the xc registers before staging.
    if (g == 0) {
        unsigned p[14];
        p[0] = (unsigned)a0.x * 18u;          p[1] = (500u + a0.y) * 18u;
        p[2] = (550u + a0.z) * 18u;           p[3] = (650u + a0.w) * 18u;
        p[4] = (653u + a1.y) * 18u;           p[5] = (663u + a1.z) * 18u;
        p[6] = (683u + a1.w) * 18u;           p[7] = (783u + a2.x) * 18u;
        p[8] = (785u + a2.y) * 18u;           p[9] = (787u + a2.w) * 18u;
        p[10] = (791u + a3.x) * 18u;          p[11] = (795u + a3.y) * 18u;
        p[12] = (845u + a3.w) * 18u;          p[13] = (855u + a16) * 18u;
        #pragma unroll
        for (int j = 0; j < 7; ++j) prl[rl * 7 + j] = p[2*j] | (p[2*j+1] << 16);
        unsigned q[14];
        q[0] = (unsigned)c0.x * 18u;          q[1] = (500u + c0.y) * 18u;
        q[2] = (550u + c0.z) * 18u;           q[3] = (650u + c0.w) * 18u;
        q[4] = (653u + c1.y) * 18u;           q[5] = (663u + c1.z) * 18u;
        q[6] = (683u + c1.w) * 18u;           q[7] = (783u + c2.x) * 18u;
        q[8] = (785u + c2.y) * 18u;           q[9] = (787u + c2.w) * 18u;
        q[10] = (791u + c3.x) * 18u;          q[11] = (795u + c3.y) * 18u;
        q[12] = (845u + c3.w) * 18u;          q[13] = (855u + c16) * 18u;
        #pragma unroll
        for (int j = 0; j < 7; ++j) prl[(RPP + rl) * 7 + j] = q[2*j] | (q[2*j+1] << 16);
    }

    if (tid < 24) {
        float a = 0.f;
        if (tid < NN) {
            #pragma unroll
            for (int d = 0; d < ED; ++d) a += W_num[d * NN + tid];
        }
        wsum[tid] = a;
    }

    // ---- Stage the 862-row table slice (covers all outstanding latencies) ----
    for (int i = tid; i < SROWS * 4; i += BLK) {
        const int r = i >> 2, qd = i & 3;
        const int d = (r < 653) ? 0 : (r < 787) ? 1000000 : (r < 845) ? 1001001 : 1003001;
        *(float4*)&tab[r * SSTR + qd * 4] =
            *(const float4*)(table + (size_t)(r + d) * ED + qd * 4);
    }
    __syncthreads();

    const float b0v = bias[0];
    const float w0 = wsum[wb],     w1 = wsum[wb + 1], w2 = wsum[wb + 2],
                w3 = wsum[wb + 3], w4 = wsum[wb + 4], w5 = wsum[wb + 5];

    // pass-1 numeric loads: issued now, consumed after pass-0 (covered by its math)
    const float* xp1 = x_num + (size_t)row1 * NN;
    const float4u xa1 = *(const float4u*)(xp1 + wb);
    float xb0_1, xb1_1;
    if (g < 3) { const float2u t = *(const float2u*)(xp1 + wb + 4); xb0_1 = t.x; xb1_1 = t.y; }
    else       { xb0_1 = xp1[22]; xb1_1 = 0.f; }

    // ================= PASS 0 =================
    {
        unsigned pk[7];
        #pragma unroll
        for (int j = 0; j < 7; ++j) pk[j] = prl[rl * 7 + j];

        float lin = xa0.x * w0 + xa0.y * w1 + xa0.z * w2 + xa0.w * w3
                  + xb0_0 * w4 + xb1_0 * w5;

        float s0 = 0.f, s1 = 0.f, s2 = 0.f, s3 = 0.f, sq = 0.f;
        #pragma unroll
        for (int j = 0; j < 7; ++j) {
            acc4(*(const float4*)&tab[(pk[j] & 0xffffu) + g * 4], s0, s1, s2, s3, sq);
            acc4(*(const float4*)&tab[(pk[j] >> 16)     + g * 4], s0, s1, s2, s3, sq);
        }
        acc4(gv00, s0, s1, s2, s3, sq);
        acc4(gv01, s0, s1, s2, s3, sq);
        acc4(gv02, s0, s1, s2, s3, sq);

        float contrib = (s0 + s1 + s2 + s3) + lin
                      + 0.5f * ((s0 * s0 + s1 * s1 + s2 * s2 + s3 * s3) - sq);
        contrib += __shfl_xor(contrib, 1);
        contrib += __shfl_xor(contrib, 2);
        if (g == 0) out[row0] = b0v + contrib;
    }

    // ================= PASS 1 =================
    {
        unsigned pk[7];
        #pragma unroll
        for (int j = 0; j < 7; ++j) pk[j] = prl[(RPP + rl) * 7 + j];

        float lin = xa1.x * w0 + xa1.y * w1 + xa1.z * w2 + xa1.w * w3
                  + xb0_1 * w4 + xb1_1 * w5;

        float s0 = 0.f, s1 = 0.f, s2 = 0.f, s3 = 0.f, sq = 0.f;
        #pragma unroll
        for (int j = 0; j < 7; ++j) {
            acc4(*(const float4*)&tab[(pk[j] & 0xffffu) + g * 4], s0, s1, s2, s3, sq);
            acc4(*(const float4*)&tab[(pk[j] >> 16)     + g * 4], s0, s1, s2, s3, sq);
        }
        acc4(gv10, s0, s1, s2, s3, sq);
        acc4(gv11, s0, s1, s2, s3, sq);
        acc4(gv12, s0, s1, s2, s3, sq);

        float contrib = (s0 + s1 + s2 + s3) + lin
                      + 0.5f * ((s0 * s0 + s1 * s1 + s2 * s2 + s3 * s3) - sq);
        contrib += __shfl_xor(contrib, 1);
        contrib += __shfl_xor(contrib, 2);
        if (g == 0) out[row1] = b0v + contrib;
    }
}

extern "C" void kernel_launch(void* const* d_in, const int* in_sizes, int n_in,
                              void* d_out, int out_size, void* d_ws, size_t ws_size,
                              hipStream_t stream) {
    const int*   x_cat = (const int*)  d_in[0];
    const float* x_num = (const float*)d_in[1];
    const float* table = (const float*)d_in[2];
    const float* W_num = (const float*)d_in[3];
    const float* bias  = (const float*)d_in[4];
    float* out = (float*)d_out;

    const int nrows = out_size;                 // 262144
    const int grid = (nrows + RPB - 1) / RPB;   // 512
    ffm_fwd_kernel<<<grid, BLK, 0, stream>>>(x_cat, x_num, table, W_num, bias, out, nrows);
}

// Round 10
// 18.168 us; speedup vs baseline: 1.9204x; 1.9204x over previous
//
#include <hip/hip_runtime.h>

#define NF 17
#define NN 23
#define ED 16
#define BLK 1024
#define RPP 256      // rows per pass = BLK/4
#define RPB 512      // rows per block (2 passes); grid*RPB == nrows exactly
#define SROWS 862    // packed rows of the 14 small-vocab fields
#define SSTR 20      // padded floats per LDS row (80 B)

typedef int   int4u    __attribute__((ext_vector_type(4), aligned(4)));
typedef float float4u  __attribute__((ext_vector_type(4), aligned(4)));
typedef float float2u  __attribute__((ext_vector_type(2), aligned(4)));
typedef float float2v  __attribute__((ext_vector_type(2)));

// packed accumulate: 2x v_pk_add_f32 + 2x v_pk_fma_f32 per field
__device__ __forceinline__ void acc4(const float4 v, float2v& sa, float2v& sb,
                                     float2v& sq2) {
    const float2v lo = {v.x, v.y};
    const float2v hi = {v.z, v.w};
    sa += lo;
    sb += hi;
    sq2 += lo * lo;
    sq2 += hi * hi;
}

__global__ __launch_bounds__(BLK, 8) void ffm_fwd_kernel(
    const int* __restrict__ x_cat,
    const float* __restrict__ x_num,
    const float* __restrict__ table,
    const float* __restrict__ W_num,
    const float* __restrict__ bias,
    float* __restrict__ out,
    int nrows)
{
    __shared__ float tab[SROWS * SSTR];   // 68,960 B -> 2 blocks/CU
    __shared__ float wsum[24];            // padded; wsum[23] = 0

    const int tid = threadIdx.x;
    const int rl  = tid >> 2;   // local row within pass
    const int g   = tid & 3;    // dim-group: dims [4g, 4g+4)
    const int wb  = 6 * g;

    const int row0 = blockIdx.x * RPB + rl;    // grid*RPB == nrows, no guards
    const int row1 = row0 + RPP;

    // ---- Pass-0 prefetch BEFORE staging: x_cat, then its 3 gathers ----
    const int* xc0 = x_cat + (size_t)row0 * NF;
    const int4u a0 = *(const int4u*)(xc0);
    const int4u a1 = *(const int4u*)(xc0 + 4);
    const int4u a2 = *(const int4u*)(xc0 + 8);
    const int4u a3 = *(const int4u*)(xc0 + 12);
    const int  a16 = xc0[16];
    const float4 gv00 = *(const float4*)(table + (size_t)(a1.x +     653) * ED + g * 4);
    const float4 gv01 = *(const float4*)(table + (size_t)(a2.z + 1000787) * ED + g * 4);
    const float4 gv02 = *(const float4*)(table + (size_t)(a3.z + 1001846) * ED + g * 4);

    const float* xp0 = x_num + (size_t)row0 * NN;
    const float4u xa0 = *(const float4u*)(xp0 + wb);
    float xb0_0, xb1_0;
    if (g < 3) { const float2u t = *(const float2u*)(xp0 + wb + 4); xb0_0 = t.x; xb1_0 = t.y; }
    else       { xb0_0 = xp0[22]; xb1_0 = 0.f; }

    if (tid < 24) {
        float a = 0.f;
        if (tid < NN) {
            #pragma unroll
            for (int d = 0; d < ED; ++d) a += W_num[d * NN + tid];
        }
        wsum[tid] = a;
    }

    // ---- Stage the 14 small-vocab fields (862 rows, 55 KB) once per block ----
    for (int i = tid; i < SROWS * 4; i += BLK) {
        const int r = i >> 2, q = i & 3;
        const int d = (r < 653) ? 0 : (r < 787) ? 1000000 : (r < 845) ? 1001001 : 1003001;
        *(float4*)&tab[r * SSTR + q * 4] =
            *(const float4*)(table + (size_t)(r + d) * ED + q * 4);
    }
    __syncthreads();

    const float b0 = bias[0];
    // packed wsum slice for dims [6g, 6g+6)
    const float2v wp0 = {wsum[wb],     wsum[wb + 1]};
    const float2v wp1 = {wsum[wb + 2], wsum[wb + 3]};
    const float2v wp2 = {wsum[wb + 4], wsum[wb + 5]};

    // ---- Prefetch pass-1 indices ----
    const int* xc1 = x_cat + (size_t)row1 * NF;
    const int4u c0 = *(const int4u*)(xc1);
    const int4u c1 = *(const int4u*)(xc1 + 4);
    const int4u c2 = *(const int4u*)(xc1 + 8);
    const int4u c3 = *(const int4u*)(xc1 + 12);
    const int  c16 = xc1[16];

    // ---- Pass 0 math ----
    {
        float2v lv = {0.f, 0.f};
        lv += float2v{xa0.x, xa0.y} * wp0;
        lv += float2v{xa0.z, xa0.w} * wp1;
        lv += float2v{xb0_0, xb1_0} * wp2;

        int pr[14];
        pr[0]  = a0.x;        pr[1]  = 500 + a0.y;  pr[2]  = 550 + a0.z;
        pr[3]  = 650 + a0.w;  pr[4]  = 653 + a1.y;  pr[5]  = 663 + a1.z;
        pr[6]  = 683 + a1.w;  pr[7]  = 783 + a2.x;  pr[8]  = 785 + a2.y;
        pr[9]  = 787 + a2.w;  pr[10] = 791 + a3.x;  pr[11] = 795 + a3.y;
        pr[12] = 845 + a3.w;  pr[13] = 855 + a16;

        float2v sa = {0.f, 0.f}, sb = {0.f, 0.f}, sq2 = {0.f, 0.f};
        #pragma unroll
        for (int k = 0; k < 14; ++k)
            acc4(*(const float4*)&tab[pr[k] * SSTR + g * 4], sa, sb, sq2);

        acc4(gv00, sa, sb, sq2);
        acc4(gv01, sa, sb, sq2);
        acc4(gv02, sa, sb, sq2);

        const float s0 = sa.x, s1 = sa.y, s2 = sb.x, s3 = sb.y;
        const float sq = sq2.x + sq2.y;
        float contrib = (s0 + s1 + s2 + s3) + (lv.x + lv.y)
                      + 0.5f * ((s0 * s0 + s1 * s1 + s2 * s2 + s3 * s3) - sq);
        contrib += __shfl_xor(contrib, 1);
        contrib += __shfl_xor(contrib, 2);
        if (g == 0) out[row0] = b0 + contrib;
    }

    // ---- Pass-1 gathers (indices already resident) + x_num ----
    const float4 gv10 = *(const float4*)(table + (size_t)(c1.x +     653) * ED + g * 4);
    const float4 gv11 = *(const float4*)(table + (size_t)(c2.z + 1000787) * ED + g * 4);
    const float4 gv12 = *(const float4*)(table + (size_t)(c3.z + 1001846) * ED + g * 4);

    const float* xp1 = x_num + (size_t)row1 * NN;
    const float4u xa1 = *(const float4u*)(xp1 + wb);
    float xb0_1, xb1_1;
    if (g < 3) { const float2u t = *(const float2u*)(xp1 + wb + 4); xb0_1 = t.x; xb1_1 = t.y; }
    else       { xb0_1 = xp1[22]; xb1_1 = 0.f; }

    // ---- Pass 1 math ----
    {
        float2v lv = {0.f, 0.f};
        lv += float2v{xa1.x, xa1.y} * wp0;
        lv += float2v{xa1.z, xa1.w} * wp1;
        lv += float2v{xb0_1, xb1_1} * wp2;

        int pr[14];
        pr[0]  = c0.x;        pr[1]  = 500 + c0.y;  pr[2]  = 550 + c0.z;
        pr[3]  = 650 + c0.w;  pr[4]  = 653 + c1.y;  pr[5]  = 663 + c1.z;
        pr[6]  = 683 + c1.w;  pr[7]  = 783 + c2.x;  pr[8]  = 785 + c2.y;
        pr[9]  = 787 + c2.w;  pr[10] = 791 + c3.x;  pr[11] = 795 + c3.y;
        pr[12] = 845 + c3.w;  pr[13] = 855 + c16;

        float2v sa = {0.f, 0.f}, sb = {0.f, 0.f}, sq2 = {0.f, 0.f};
        #pragma unroll
        for (int k = 0; k < 14; ++k)
            acc4(*(const float4*)&tab[pr[k] * SSTR + g * 4], sa, sb, sq2);

        acc4(gv10, sa, sb, sq2);
        acc4(gv11, sa, sb, sq2);
        acc4(gv12, sa, sb, sq2);

        const float s0 = sa.x, s1 = sa.y, s2 = sb.x, s3 = sb.y;
        const float sq = sq2.x + sq2.y;
        float contrib = (s0 + s1 + s2 + s3) + (lv.x + lv.y)
                      + 0.5f * ((s0 * s0 + s1 * s1 + s2 * s2 + s3 * s3) - sq);
        contrib += __shfl_xor(contrib, 1);
        contrib += __shfl_xor(contrib, 2);
        if (g == 0) out[row1] = b0 + contrib;
    }
}

extern "C" void kernel_launch(void* const* d_in, const int* in_sizes, int n_in,
                              void* d_out, int out_size, void* d_ws, size_t ws_size,
                              hipStream_t stream) {
    const int*   x_cat = (const int*)  d_in[0];
    const float* x_num = (const float*)d_in[1];
    const float* table = (const float*)d_in[2];
    const float* W_num = (const float*)d_in[3];
    const float* bias  = (const float*)d_in[4];
    float* out = (float*)d_out;

    const int nrows = out_size;                 // 262144
    const int grid = (nrows + RPB - 1) / RPB;   // 512
    ffm_fwd_kernel<<<grid, BLK, 0, stream>>>(x_cat, x_num, table, W_num, bias, out, nrows);
}